// Round 11
// baseline (388.617 us; speedup 1.0000x reference)
//
#include <hip/hip_runtime.h>
#include <hip/hip_bf16.h>

#define MODEL 2048
#define NHEAD 16
#define HDIM  128
#define BB    2
#define LL    2048
#define N1    (3*MODEL)      // 6144
#define MTOT  (BB*LL)        // 4096

typedef __hip_bfloat16 bf16;
typedef __attribute__((ext_vector_type(8))) short bf16x8;
typedef __attribute__((ext_vector_type(4))) float f32x4;

static __device__ __forceinline__ f32x4 mfma16(bf16x8 a, bf16x8 b, f32x4 c) {
  return __builtin_amdgcn_mfma_f32_16x16x32_bf16(a, b, c, 0, 0, 0);
}

// async global->LDS DMA, 16B per lane; LDS base wave-uniform, dest linear
static __device__ __forceinline__ void gl_lds16(const void* g, void* l) {
  __builtin_amdgcn_global_load_lds(
      (const __attribute__((address_space(1))) unsigned int*)g,
      (__attribute__((address_space(3))) unsigned int*)l, 16, 0, 0);
}

// ---------------- prep: f32 -> bf16 (vectorized x4) ----------------
__global__ void k_cvt(const float* __restrict__ in, bf16* __restrict__ out, int n4) {
  int i = blockIdx.x * blockDim.x + threadIdx.x;
  if (i < n4) {
    float4 v = ((const float4*)in)[i];
    bf16* o = out + (size_t)i * 4;
    o[0] = __float2bfloat16(v.x);
    o[1] = __float2bfloat16(v.y);
    o[2] = __float2bfloat16(v.z);
    o[3] = __float2bfloat16(v.w);
  }
}

// ---------------- prep: transpose f32 [R][C] -> bf16 [C][R] ----------------
__global__ __launch_bounds__(256)
void k_transpose(const float* __restrict__ in, bf16* __restrict__ out, int R, int C) {
  __shared__ float t[32][33];
  const int c0 = blockIdx.x * 32, r0 = blockIdx.y * 32;
  const int tx = threadIdx.x & 31;
  const int ty = threadIdx.x >> 5;   // 0..7
#pragma unroll
  for (int i = 0; i < 4; ++i)
    t[ty + 8*i][tx] = in[(size_t)(r0 + ty + 8*i) * C + c0 + tx];
  __syncthreads();
#pragma unroll
  for (int i = 0; i < 4; ++i)
    out[(size_t)(c0 + ty + 8*i) * R + r0 + tx] = __float2bfloat16(t[tx][ty + 8*i]);
}

// ============ 128x128 GEMM, BK=32, 4-buffer pipeline, 2 blocks/CU ============
// r9-proven config (best GEMM measured: 580 TF on GEMM1): 512 threads, 8 waves
// (2Mx4N), K-tiles of 32 through 4 LDS buffers, A @0 (32KB) B @32768; 64KB ->
// 2 blocks/CU; cross-BLOCK drift overlaps LDS bursts of one block with MFMA
// bursts of the other (intra-block lockstep mandatory: staging is distributed
// across waves -> collective barrier per tile, r8 lesson).
// Per tile: 6 ds_reads; stage t+3 (2 gl_lds); lgkm0; 8 MFMA; vmcnt(4)
// completes t+1 (outstanding = t+1..t+3 = 6); barrier. Slot swizzle (r6,
// 0-conflict verified): read 16B-slot = lkg ^ ((lr>>1)&3); staged via
// inverse-permuted SOURCE slot (l&3)^((l>>3)&3), linear LDS dest.
// EPI==1: RoPE + scatter Q/K row-major + V^T ; EPI==2: bias + f32 out.

#define BARRIER __builtin_amdgcn_s_barrier()
#define SCHED0  __builtin_amdgcn_sched_barrier(0)
#define PRIO1 __builtin_amdgcn_s_setprio(1)
#define PRIO0 __builtin_amdgcn_s_setprio(0)

template<int EPI>
__global__ __launch_bounds__(512, 4)
void k_gemmP(const bf16* __restrict__ A, const bf16* __restrict__ BT,
             int M, int N, int K,
             float* __restrict__ Cout, const float* __restrict__ bias,
             bf16* __restrict__ Qb, bf16* __restrict__ Kb, bf16* __restrict__ VTb,
             const float* __restrict__ cosT, const float* __restrict__ sinT)
{
  constexpr int ABUF = 8192;           // one A tile (128 rows x 64B)
  constexpr int BBUF = 8192;
  constexpr int AREG = 4 * ABUF;       // 32768
  extern __shared__ char smem[];       // 65536 B

  const int tid = threadIdx.x;
  const int wid = tid >> 6, lane = tid & 63;
  const int wm = wid >> 2, wn = wid & 3;       // wave grid 2(M) x 4(N)
  const int lr = lane & 15, lkg = lane >> 4;

  // XCD-aware block mapping: column-major chunked (nwg % 8 == 0)
  const int nby = M >> 7;
  const int qq = ((N >> 7) * nby) >> 3;
  const int lin = (blockIdx.x & 7) * qq + (blockIdx.x >> 3);
  const int m0 = (lin % nby) << 7, n0 = (lin / nby) << 7;

  // staging: wave wid owns 16 rows; source slot carries inverse swizzle
  const int scol = ((lane & 3) ^ ((lane >> 3) & 3)) * 8;   // bf16 elems
  const bf16* Asrc = A  + (size_t)(m0 + wid*16 + (lane >> 2)) * K + scol;
  const bf16* Bsrc = BT + (size_t)(n0 + wid*16 + (lane >> 2)) * K + scol;

  auto stageA = [&](int t) {
    gl_lds16(Asrc + t*32, smem + (t & 3)*ABUF + wid*1024);
  };
  auto stageB = [&](int t) {
    gl_lds16(Bsrc + t*32, smem + AREG + (t & 3)*BBUF + wid*1024);
  };

  // ds_read fragment bases (row = 64B, slot XOR-swizzled by row bits 1-2)
  const int slotX = (lkg ^ ((lr >> 1) & 3)) * 16;
  const int aBase = wm*4096 + lr*64 + slotX;   // rows wm*64 + mf*16 + lr
  const int bBase = wn*2048 + lr*64 + slotX;   // rows wn*32 + nf*16 + lr

  const f32x4 vzero = {0.f, 0.f, 0.f, 0.f};
  f32x4 acc[4][2];
#pragma unroll
  for (int i = 0; i < 4; ++i)
#pragma unroll
    for (int j = 0; j < 2; ++j) acc[i][j] = vzero;

  const int nt = K >> 5;              // K-tiles of 32 (>= 4)

  // prologue: stage tiles 0,1,2 -> wait until tile 0's 2 loads complete
  stageA(0); stageB(0); stageA(1); stageB(1); stageA(2); stageB(2);
  asm volatile("s_waitcnt vmcnt(4)" ::: "memory");
  SCHED0; BARRIER;

  for (int t = 0; t < nt; ++t) {
    const int bufA = (t & 3) * ABUF;
    const int bufB = AREG + (t & 3) * BBUF;
    const int ts   = (t + 3 < nt) ? t + 3 : nt - 1;   // clamp: same-data dup
    bf16x8 aFr[4], bFr[2];

#pragma unroll
    for (int mf = 0; mf < 4; ++mf)
      aFr[mf] = *(const bf16x8*)(smem + bufA + aBase + mf*1024);
#pragma unroll
    for (int nf = 0; nf < 2; ++nf)
      bFr[nf] = *(const bf16x8*)(smem + bufB + bBase + nf*1024);
    stageA(ts); stageB(ts);

    asm volatile("s_waitcnt lgkmcnt(0)" ::: "memory");
    SCHED0;
    PRIO1;
#pragma unroll
    for (int mf = 0; mf < 4; ++mf)
#pragma unroll
      for (int nf = 0; nf < 2; ++nf)
        acc[mf][nf] = mfma16(aFr[mf], bFr[nf], acc[mf][nf]);
    PRIO0;
    // complete tile t+1's loads (outstanding = tiles t+1..t+3 = 6 loads)
    asm volatile("s_waitcnt vmcnt(4)" ::: "memory");
    SCHED0;
    BARRIER;                          // collective: tile t+1 visible to all
  }

  if constexpr (EPI == 1) {
    const float inv_sqrt_d = 0.08838834764831845f;  // 1/sqrt(128)
#pragma unroll
    for (int nf = 0; nf < 2; ++nf) {
      const int gcb = n0 + wn*32 + nf*16;           // wave-uniform, mult of 16
      const int section = gcb >> 11;                // 0=q 1=k 2=v
      const int cc = (gcb & 2047) + lr;
      const int h = cc >> 7, d = cc & 127;
#pragma unroll
      for (int mf = 0; mf < 4; ++mf) {
#pragma unroll
        for (int reg = 0; reg < 4; ++reg) {
          const int grow = m0 + wm*64 + mf*16 + lkg*4 + reg;
          const int bidx = grow >> 11, lseq = grow & 2047;
          float val = acc[mf][nf][reg];
          if (section < 2) {
            float p = __shfl_xor(val, 1);           // RoPE pair partner
            const int fi = d >> 1;
            float cv = cosT[(size_t)lseq * 64 + fi];
            float sv = sinT[(size_t)lseq * 64 + fi];
            float r = (d & 1) ? fmaf(p, sv, val * cv)
                              : fmaf(val, cv, -p * sv);
            if (section == 0) {
              r *= inv_sqrt_d;
              Qb[((size_t)(bidx*NHEAD + h) * LL + lseq) * HDIM + d] = __float2bfloat16(r);
            } else {
              Kb[((size_t)(bidx*NHEAD + h) * LL + lseq) * HDIM + d] = __float2bfloat16(r);
            }
          } else {
            VTb[((size_t)(bidx*NHEAD + h) * HDIM + d) * LL + lseq] = __float2bfloat16(val);
          }
        }
      }
    }
  } else {
#pragma unroll
    for (int nf = 0; nf < 2; ++nf) {
      const int gcol = n0 + wn*32 + nf*16 + lr;
      const float bv = bias[gcol];
#pragma unroll
      for (int mf = 0; mf < 4; ++mf) {
#pragma unroll
        for (int reg = 0; reg < 4; ++reg) {
          const int grow = m0 + wm*64 + mf*16 + lkg*4 + reg;
          Cout[(size_t)grow * N + gcol] = acc[mf][nf][reg] + bv;
        }
      }
    }
  }
}

// ---------------- flash attention: 512 blocks, 1 q-tile each ----------------
// r11: grid 16x32 = 512 blocks = full 2-blocks/CU capacity (r9/r10's 256-block
// grid left half the machine idle). Complementary ordering: adjacent blocks
// (likely co-resident on a CU) get qt pairs (15-k, k) -> ~34 steps per CU.
__global__ __launch_bounds__(256, 2)
void k_attn(const bf16* __restrict__ Qb, const bf16* __restrict__ Kb,
            const bf16* __restrict__ VTb, bf16* __restrict__ attnA)
{
  __shared__ bf16 Ks[64][136];
  __shared__ bf16 Vs[128][72];
  __shared__ bf16 Ps[4][32][72];

  const int bh  = blockIdx.y;
  const int bx  = blockIdx.x;                 // 0..15
  const int qt  = (bx & 1) ? (bx >> 1) : (15 - (bx >> 1));
  const int tid = threadIdx.x;
  const int wid = tid >> 6, lane = tid & 63;
  const int lr  = lane & 15, lkg = lane >> 4;
  const int Q0  = qt * 128;
  const int q0w = Q0 + wid * 32;

  const bf16* Qh = Qb  + (size_t)bh * LL * HDIM;
  const bf16* Kh = Kb  + (size_t)bh * LL * HDIM;
  const bf16* Vh = VTb + (size_t)bh * HDIM * LL;
  const int b = bh >> 4, h = bh & 15;
  const f32x4 vzero = {0.f, 0.f, 0.f, 0.f};

  bf16x8 qf[2][4];
#pragma unroll
  for (int qr = 0; qr < 2; ++qr)
#pragma unroll
    for (int kk = 0; kk < 4; ++kk)
      qf[qr][kk] = *(const bf16x8*)(Qh + (size_t)(q0w + qr*16 + lr) * HDIM + kk*32 + lkg*8);

  f32x4 oacc[2][8];
#pragma unroll
  for (int qr = 0; qr < 2; ++qr)
#pragma unroll
    for (int db = 0; db < 8; ++db) oacc[qr][db] = vzero;
  float mrow[2][4], lrow[2][4];
#pragma unroll
  for (int qr = 0; qr < 2; ++qr)
#pragma unroll
    for (int r = 0; r < 4; ++r) { mrow[qr][r] = -INFINITY; lrow[qr][r] = 0.f; }

  const int NT = Q0 / 64 + 2;
  bf16x8 kpre[4], vpre[4];
#pragma unroll
  for (int j = 0; j < 4; ++j) {
    const int c = j*256 + tid;
    kpre[j] = *(const bf16x8*)(Kh + (size_t)(c >> 4) * HDIM + (c & 15) * 8);
    vpre[j] = *(const bf16x8*)(Vh + (size_t)(c >> 3) * LL + (c & 7) * 8);
  }

  for (int kt = 0; kt < NT; ++kt) {
    const int kbase = kt * 64;
    __syncthreads();
#pragma unroll
    for (int j = 0; j < 4; ++j) {
      const int c = j*256 + tid;
      *(bf16x8*)&Ks[c >> 4][(c & 15) * 8] = kpre[j];
      *(bf16x8*)&Vs[c >> 3][(c & 7) * 8]  = vpre[j];
    }
    __syncthreads();
    if (kt + 1 < NT) {
#pragma unroll
      for (int j = 0; j < 4; ++j) {
        const int c = j*256 + tid;
        kpre[j] = *(const bf16x8*)(Kh + (size_t)((kt+1)*64 + (c >> 4)) * HDIM + (c & 15) * 8);
        vpre[j] = *(const bf16x8*)(Vh + (size_t)(c >> 3) * LL + (kt+1)*64 + (c & 7) * 8);
      }
    }
    if (kbase <= q0w + 31) {
      f32x4 s[2][4];
#pragma unroll
      for (int qr = 0; qr < 2; ++qr)
#pragma unroll
        for (int c = 0; c < 4; ++c) s[qr][c] = vzero;
#pragma unroll
      for (int c = 0; c < 4; ++c) {
        bf16x8 kf[4];
#pragma unroll
        for (int kk = 0; kk < 4; ++kk)
          kf[kk] = *(const bf16x8*)&Ks[c*16 + lr][kk*32 + lkg*8];
#pragma unroll
        for (int qr = 0; qr < 2; ++qr)
#pragma unroll
          for (int kk = 0; kk < 4; ++kk)
            s[qr][c] = mfma16(qf[qr][kk], kf[kk], s[qr][c]);
      }
#pragma unroll
      for (int qr = 0; qr < 2; ++qr) {
        float scl4[4];
#pragma unroll
        for (int reg = 0; reg < 4; ++reg) {
          const int row = q0w + qr*16 + lkg*4 + reg;
          float v0 = (kbase      + lr <= row) ? s[qr][0][reg] : -INFINITY;
          float v1 = (kbase + 16 + lr <= row) ? s[qr][1][reg] : -INFINITY;
          float v2 = (kbase + 32 + lr <= row) ? s[qr][2][reg] : -INFINITY;
          float v3 = (kbase + 48 + lr <= row) ? s[qr][3][reg] : -INFINITY;
          float tm = fmaxf(fmaxf(v0, v1), fmaxf(v2, v3));
          tm = fmaxf(tm, __shfl_xor(tm, 1));
          tm = fmaxf(tm, __shfl_xor(tm, 2));
          tm = fmaxf(tm, __shfl_xor(tm, 4));
          tm = fmaxf(tm, __shfl_xor(tm, 8));
          const float mnew = fmaxf(mrow[qr][reg], tm);
          const float scl  = __expf(mrow[qr][reg] - mnew);
          mrow[qr][reg] = mnew;
          float p0 = __expf(v0 - mnew);
          float p1 = __expf(v1 - mnew);
          float p2 = __expf(v2 - mnew);
          float p3 = __expf(v3 - mnew);
          float rs = (p0 + p1) + (p2 + p3);
          rs += __shfl_xor(rs, 1);
          rs += __shfl_xor(rs, 2);
          rs += __shfl_xor(rs, 4);
          rs += __shfl_xor(rs, 8);
          lrow[qr][reg] = lrow[qr][reg] * scl + rs;
          scl4[reg] = scl;
          const int prow = qr*16 + lkg*4 + reg;
          Ps[wid][prow][lr]      = __float2bfloat16(p0);
          Ps[wid][prow][16 + lr] = __float2bfloat16(p1);
          Ps[wid][prow][32 + lr] = __float2bfloat16(p2);
          Ps[wid][prow][48 + lr] = __float2bfloat16(p3);
        }
#pragma unroll
        for (int db = 0; db < 8; ++db) {
          oacc[qr][db][0] *= scl4[0]; oacc[qr][db][1] *= scl4[1];
          oacc[qr][db][2] *= scl4[2]; oacc[qr][db][3] *= scl4[3];
        }
      }
      asm volatile("s_waitcnt lgkmcnt(0)" ::: "memory");
      __builtin_amdgcn_sched_barrier(0);
      bf16x8 pf[2][2];
#pragma unroll
      for (int qr = 0; qr < 2; ++qr)
#pragma unroll
        for (int k2 = 0; k2 < 2; ++k2)
          pf[qr][k2] = *(const bf16x8*)&Ps[wid][qr*16 + lr][k2*32 + lkg*8];
#pragma unroll
      for (int db = 0; db < 8; ++db) {
        bf16x8 vf0 = *(const bf16x8*)&Vs[db*16 + lr][lkg*8];
        bf16x8 vf1 = *(const bf16x8*)&Vs[db*16 + lr][32 + lkg*8];
#pragma unroll
        for (int qr = 0; qr < 2; ++qr) {
          oacc[qr][db] = mfma16(pf[qr][0], vf0, oacc[qr][db]);
          oacc[qr][db] = mfma16(pf[qr][1], vf1, oacc[qr][db]);
        }
      }
    }
  }

#pragma unroll
  for (int qr = 0; qr < 2; ++qr)
#pragma unroll
    for (int reg = 0; reg < 4; ++reg) {
      const float inv = 1.0f / lrow[qr][reg];
      const int row = q0w + qr*16 + lkg*4 + reg;
      bf16* dst = attnA + ((size_t)(b*LL + row)) * MODEL + h * HDIM;
#pragma unroll
      for (int db = 0; db < 8; ++db)
        dst[db*16 + lr] = __float2bfloat16(oacc[qr][db][reg] * inv);
    }
}

// ---------------- launch ----------------
extern "C" void kernel_launch(void* const* d_in, const int* in_sizes, int n_in,
                              void* d_out, int out_size, void* d_ws, size_t ws_size,
                              hipStream_t stream)
{
  const float* x    = (const float*)d_in[0];
  const float* cosT = (const float*)d_in[1];
  const float* sinT = (const float*)d_in[2];
  const float* Wqkv = (const float*)d_in[3];
  const float* Wc   = (const float*)d_in[4];
  const float* bc   = (const float*)d_in[5];
  float* out = (float*)d_out;

  // workspace layout (bytes):
  //   x16    @ 0         : 16,777,216   (reused as attnA later)
  //   WqkvT  @ 16777216  : 25,165,824
  //   WcT    @ 41943040  :  8,388,608
  //   Qb     @ 50331648  : 16,777,216
  //   Kb     @ 67108864  : 16,777,216
  //   VTb    @ 83886080  : 16,777,216   -> total 100,663,296 B
  if (ws_size < 100663296u) return;
  char* w = (char*)d_ws;
  bf16* x16   = (bf16*)(w);
  bf16* WqkvT = (bf16*)(w + (size_t)16777216);
  bf16* WcT   = (bf16*)(w + (size_t)41943040);
  bf16* Qb    = (bf16*)(w + (size_t)50331648);
  bf16* Kb    = (bf16*)(w + (size_t)67108864);
  bf16* VTb   = (bf16*)(w + (size_t)83886080);
  bf16* attnA = x16;   // overlay: x16 dead after GEMM1

  // allow 64KB dynamic LDS (idempotent; not a stream op -> capture-safe)
  hipFuncSetAttribute(reinterpret_cast<const void*>(&k_gemmP<1>),
                      hipFuncAttributeMaxDynamicSharedMemorySize, 65536);
  hipFuncSetAttribute(reinterpret_cast<const void*>(&k_gemmP<2>),
                      hipFuncAttributeMaxDynamicSharedMemorySize, 65536);

  k_cvt<<<(MTOT*MODEL/4 + 255)/256, 256, 0, stream>>>(x, x16, MTOT*MODEL/4);
  k_transpose<<<dim3(N1/32,    MODEL/32), 256, 0, stream>>>(Wqkv, WqkvT, MODEL, N1);
  k_transpose<<<dim3(MODEL/32, MODEL/32), 256, 0, stream>>>(Wc,   WcT,   MODEL, MODEL);

  // grid 48*32 = 1536 blocks = 3 exact rounds at 2 blocks/CU
  k_gemmP<1><<<(N1/128)*(MTOT/128), 512, 65536, stream>>>(
      x16, WqkvT, MTOT, N1, MODEL,
      nullptr, nullptr, Qb, Kb, VTb, cosT, sinT);

  // grid 16*32 = 512 blocks = full 2-blocks/CU machine capacity
  k_attn<<<dim3(16, BB*NHEAD), 256, 0, stream>>>(Qb, Kb, VTb, attnA);

  // grid 16*32 = 512 blocks = 1 exact round
  k_gemmP<2><<<(MODEL/128)*(MTOT/128), 512, 65536, stream>>>(
      attnA, WcT, MTOT, MODEL, MODEL,
      out, bc, nullptr, nullptr, nullptr, nullptr, nullptr);
}

// Round 12
// 352.951 us; speedup vs baseline: 1.1011x; 1.1011x over previous
//
#include <hip/hip_runtime.h>
#include <hip/hip_bf16.h>

#define MODEL 2048
#define NHEAD 16
#define HDIM  128
#define BB    2
#define LL    2048
#define N1    (3*MODEL)      // 6144
#define MTOT  (BB*LL)        // 4096

typedef __hip_bfloat16 bf16;
typedef __attribute__((ext_vector_type(8))) short bf16x8;
typedef __attribute__((ext_vector_type(4))) float f32x4;

static __device__ __forceinline__ f32x4 mfma16(bf16x8 a, bf16x8 b, f32x4 c) {
  return __builtin_amdgcn_mfma_f32_16x16x32_bf16(a, b, c, 0, 0, 0);
}

// async global->LDS DMA, 16B per lane; LDS base wave-uniform, dest linear
static __device__ __forceinline__ void gl_lds16(const void* g, void* l) {
  __builtin_amdgcn_global_load_lds(
      (const __attribute__((address_space(1))) unsigned int*)g,
      (__attribute__((address_space(3))) unsigned int*)l, 16, 0, 0);
}

// ---------------- prep: f32 -> bf16 (vectorized x4) ----------------
__global__ void k_cvt(const float* __restrict__ in, bf16* __restrict__ out, int n4) {
  int i = blockIdx.x * blockDim.x + threadIdx.x;
  if (i < n4) {
    float4 v = ((const float4*)in)[i];
    bf16* o = out + (size_t)i * 4;
    o[0] = __float2bfloat16(v.x);
    o[1] = __float2bfloat16(v.y);
    o[2] = __float2bfloat16(v.z);
    o[3] = __float2bfloat16(v.w);
  }
}

// ---------------- prep: transpose f32 [R][C] -> bf16 [C][R] ----------------
__global__ __launch_bounds__(256)
void k_transpose(const float* __restrict__ in, bf16* __restrict__ out, int R, int C) {
  __shared__ float t[32][33];
  const int c0 = blockIdx.x * 32, r0 = blockIdx.y * 32;
  const int tx = threadIdx.x & 31;
  const int ty = threadIdx.x >> 5;   // 0..7
#pragma unroll
  for (int i = 0; i < 4; ++i)
    t[ty + 8*i][tx] = in[(size_t)(r0 + ty + 8*i) * C + c0 + tx];
  __syncthreads();
#pragma unroll
  for (int i = 0; i < 4; ++i)
    out[(size_t)(c0 + ty + 8*i) * R + r0 + tx] = __float2bfloat16(t[tx][ty + 8*i]);
}

// ====== 128x128 GEMM, BK=32, 3-buffer pipeline, 3 blocks/CU (r12) ======
// r9-proven skeleton (8 waves 2Mx4N, lockstep tile, distributed staging with
// collective barrier per tile -- r8 lesson). r12 changes:
//  (1) 3 LDS buffers (48KB) -> 3 blocks/CU (was 2): more cross-block overlap.
//      Safety (mod-3): stage(t+2) targets buf (t-1)%3 whose reads drained
//      before the t-1 tile-end barrier; per-wave vmcnt(2) at tile end leaves
//      only stage(t+2) outstanding -> t+1 resident; barrier publishes it.
//  (2) Square-ish XCD chunk map (bid%8 = XCD): XCD=(mhalf,nhalf) owns an
//      8m x (nbx/2)n chunk, m-inner traversal -> per-XCD A = 4MB (L2-fit),
//      B streamed once. Was: 32m x 6n strip, A 16MB >> L2 (FETCH 405MB).
// Slot swizzle (r6, 0-conflict verified): read 16B-slot = lkg ^ ((lr>>1)&3);
// staged via inverse-permuted SOURCE slot (l&3)^((l>>3)&3), linear LDS dest.
// EPI==1: RoPE + scatter Q/K row-major + V^T ; EPI==2: bias + f32 out.

#define BARRIER __builtin_amdgcn_s_barrier()
#define SCHED0  __builtin_amdgcn_sched_barrier(0)
#define PRIO1 __builtin_amdgcn_s_setprio(1)
#define PRIO0 __builtin_amdgcn_s_setprio(0)

template<int EPI>
__global__ __launch_bounds__(512, 4)
void k_gemmP(const bf16* __restrict__ A, const bf16* __restrict__ BT,
             int M, int N, int K,
             float* __restrict__ Cout, const float* __restrict__ bias,
             bf16* __restrict__ Qb, bf16* __restrict__ Kb, bf16* __restrict__ VTb,
             const float* __restrict__ cosT, const float* __restrict__ sinT)
{
  constexpr int ABUF = 8192;           // one A tile (128 rows x 64B)
  constexpr int BBUF = 8192;
  constexpr int AREG = 3 * ABUF;       // 24576
  extern __shared__ char smem[];       // 49152 B

  const int tid = threadIdx.x;
  const int wid = tid >> 6, lane = tid & 63;
  const int wm = wid >> 2, wn = wid & 3;       // wave grid 2(M) x 4(N)
  const int lr = lane & 15, lkg = lane >> 4;

  // XCD chunk map: xcd = bid%8 -> (mhalf = xcd>>1 of 4, nhalf = xcd&1 of 2);
  // chunk = 8 m-rows x (nbx/2) n-cols, traversal m-inner (8 share a B panel).
  const int nbx = N >> 7;                      // 48 or 16 (nby = 32 always)
  const int xcd = blockIdx.x & 7;
  const int i   = blockIdx.x >> 3;             // 0 .. nbx*4-1
  const int m0 = (((xcd >> 1) << 3) + (i & 7)) << 7;
  const int n0 = (((xcd & 1) * (nbx >> 1)) + (i >> 3)) << 7;

  // staging: wave wid owns 16 rows; source slot carries inverse swizzle
  const int scol = ((lane & 3) ^ ((lane >> 3) & 3)) * 8;   // bf16 elems
  const bf16* Asrc = A  + (size_t)(m0 + wid*16 + (lane >> 2)) * K + scol;
  const bf16* Bsrc = BT + (size_t)(n0 + wid*16 + (lane >> 2)) * K + scol;

  auto stageA = [&](int t) {
    gl_lds16(Asrc + t*32, smem + (t % 3)*ABUF + wid*1024);
  };
  auto stageB = [&](int t) {
    gl_lds16(Bsrc + t*32, smem + AREG + (t % 3)*BBUF + wid*1024);
  };

  // ds_read fragment bases (row = 64B, slot XOR-swizzled by row bits 1-2)
  const int slotX = (lkg ^ ((lr >> 1) & 3)) * 16;
  const int aBase = wm*4096 + lr*64 + slotX;   // rows wm*64 + mf*16 + lr
  const int bBase = wn*2048 + lr*64 + slotX;   // rows wn*32 + nf*16 + lr

  const f32x4 vzero = {0.f, 0.f, 0.f, 0.f};
  f32x4 acc[4][2];
#pragma unroll
  for (int ii = 0; ii < 4; ++ii)
#pragma unroll
    for (int j = 0; j < 2; ++j) acc[ii][j] = vzero;

  const int nt = K >> 5;              // K-tiles of 32 (>= 3)

  // prologue: stage tiles 0,1 -> wait until tile 0's 2 loads complete
  stageA(0); stageB(0); stageA(1); stageB(1);
  asm volatile("s_waitcnt vmcnt(2)" ::: "memory");
  SCHED0; BARRIER;

  for (int t = 0; t < nt; ++t) {
    const int bufA = (t % 3) * ABUF;
    const int bufB = AREG + (t % 3) * BBUF;
    const int ts   = (t + 2 < nt) ? t + 2 : nt - 1;   // clamp: same-data dup
    bf16x8 aFr[4], bFr[2];

#pragma unroll
    for (int mf = 0; mf < 4; ++mf)
      aFr[mf] = *(const bf16x8*)(smem + bufA + aBase + mf*1024);
#pragma unroll
    for (int nf = 0; nf < 2; ++nf)
      bFr[nf] = *(const bf16x8*)(smem + bufB + bBase + nf*1024);
    stageA(ts); stageB(ts);

    asm volatile("s_waitcnt lgkmcnt(0)" ::: "memory");
    SCHED0;
    PRIO1;
#pragma unroll
    for (int mf = 0; mf < 4; ++mf)
#pragma unroll
      for (int nf = 0; nf < 2; ++nf)
        acc[mf][nf] = mfma16(aFr[mf], bFr[nf], acc[mf][nf]);
    PRIO0;
    // complete tile t+1's loads (only stage(t+2)'s 2 loads stay in flight)
    asm volatile("s_waitcnt vmcnt(2)" ::: "memory");
    SCHED0;
    BARRIER;                          // collective: tile t+1 visible to all
  }

  if constexpr (EPI == 1) {
    const float inv_sqrt_d = 0.08838834764831845f;  // 1/sqrt(128)
#pragma unroll
    for (int nf = 0; nf < 2; ++nf) {
      const int gcb = n0 + wn*32 + nf*16;           // wave-uniform, mult of 16
      const int section = gcb >> 11;                // 0=q 1=k 2=v
      const int cc = (gcb & 2047) + lr;
      const int h = cc >> 7, d = cc & 127;
#pragma unroll
      for (int mf = 0; mf < 4; ++mf) {
#pragma unroll
        for (int reg = 0; reg < 4; ++reg) {
          const int grow = m0 + wm*64 + mf*16 + lkg*4 + reg;
          const int bidx = grow >> 11, lseq = grow & 2047;
          float val = acc[mf][nf][reg];
          if (section < 2) {
            float p = __shfl_xor(val, 1);           // RoPE pair partner
            const int fi = d >> 1;
            float cv = cosT[(size_t)lseq * 64 + fi];
            float sv = sinT[(size_t)lseq * 64 + fi];
            float r = (d & 1) ? fmaf(p, sv, val * cv)
                              : fmaf(val, cv, -p * sv);
            if (section == 0) {
              r *= inv_sqrt_d;
              Qb[((size_t)(bidx*NHEAD + h) * LL + lseq) * HDIM + d] = __float2bfloat16(r);
            } else {
              Kb[((size_t)(bidx*NHEAD + h) * LL + lseq) * HDIM + d] = __float2bfloat16(r);
            }
          } else {
            VTb[((size_t)(bidx*NHEAD + h) * HDIM + d) * LL + lseq] = __float2bfloat16(val);
          }
        }
      }
    }
  } else {
#pragma unroll
    for (int nf = 0; nf < 2; ++nf) {
      const int gcol = n0 + wn*32 + nf*16 + lr;
      const float bv = bias[gcol];
#pragma unroll
      for (int mf = 0; mf < 4; ++mf) {
#pragma unroll
        for (int reg = 0; reg < 4; ++reg) {
          const int grow = m0 + wm*64 + mf*16 + lkg*4 + reg;
          Cout[(size_t)grow * N + gcol] = acc[mf][nf][reg] + bv;
        }
      }
    }
  }
}

// ---------------- flash attention: balanced q-tile pairing (r9 exact) --------
// Block bx handles q-tiles (15-bx) then (bx): per-block KV work uniform
// (17 tile-units) -> robust to ANY block->CU/XCD placement.
__global__ __launch_bounds__(256, 2)
void k_attn(const bf16* __restrict__ Qb, const bf16* __restrict__ Kb,
            const bf16* __restrict__ VTb, bf16* __restrict__ attnA)
{
  __shared__ bf16 Ks[64][136];
  __shared__ bf16 Vs[128][72];
  __shared__ bf16 Ps[4][32][72];

  const int bh  = blockIdx.y;
  const int bx  = blockIdx.x;                 // 0..7
  const int tid = threadIdx.x;
  const int wid = tid >> 6, lane = tid & 63;
  const int lr  = lane & 15, lkg = lane >> 4;

  const bf16* Qh = Qb  + (size_t)bh * LL * HDIM;
  const bf16* Kh = Kb  + (size_t)bh * LL * HDIM;
  const bf16* Vh = VTb + (size_t)bh * HDIM * LL;
  const int b = bh >> 4, h = bh & 15;
  const f32x4 vzero = {0.f, 0.f, 0.f, 0.f};

  for (int pp = 0; pp < 2; ++pp) {
    const int qt  = pp ? bx : (15 - bx);      // heavy tile first
    const int Q0  = qt * 128;
    const int q0w = Q0 + wid * 32;

    bf16x8 qf[2][4];
#pragma unroll
    for (int qr = 0; qr < 2; ++qr)
#pragma unroll
      for (int kk = 0; kk < 4; ++kk)
        qf[qr][kk] = *(const bf16x8*)(Qh + (size_t)(q0w + qr*16 + lr) * HDIM + kk*32 + lkg*8);

    f32x4 oacc[2][8];
#pragma unroll
    for (int qr = 0; qr < 2; ++qr)
#pragma unroll
      for (int db = 0; db < 8; ++db) oacc[qr][db] = vzero;
    float mrow[2][4], lrow[2][4];
#pragma unroll
    for (int qr = 0; qr < 2; ++qr)
#pragma unroll
      for (int r = 0; r < 4; ++r) { mrow[qr][r] = -INFINITY; lrow[qr][r] = 0.f; }

    const int NT = Q0 / 64 + 2;
    bf16x8 kpre[4], vpre[4];
#pragma unroll
    for (int j = 0; j < 4; ++j) {
      const int c = j*256 + tid;
      kpre[j] = *(const bf16x8*)(Kh + (size_t)(c >> 4) * HDIM + (c & 15) * 8);
      vpre[j] = *(const bf16x8*)(Vh + (size_t)(c >> 3) * LL + (c & 7) * 8);
    }

    for (int kt = 0; kt < NT; ++kt) {
      const int kbase = kt * 64;
      __syncthreads();
#pragma unroll
      for (int j = 0; j < 4; ++j) {
        const int c = j*256 + tid;
        *(bf16x8*)&Ks[c >> 4][(c & 15) * 8] = kpre[j];
        *(bf16x8*)&Vs[c >> 3][(c & 7) * 8]  = vpre[j];
      }
      __syncthreads();
      if (kt + 1 < NT) {
#pragma unroll
        for (int j = 0; j < 4; ++j) {
          const int c = j*256 + tid;
          kpre[j] = *(const bf16x8*)(Kh + (size_t)((kt+1)*64 + (c >> 4)) * HDIM + (c & 15) * 8);
          vpre[j] = *(const bf16x8*)(Vh + (size_t)(c >> 3) * LL + (kt+1)*64 + (c & 7) * 8);
        }
      }
      if (kbase <= q0w + 31) {
        f32x4 s[2][4];
#pragma unroll
        for (int qr = 0; qr < 2; ++qr)
#pragma unroll
          for (int c = 0; c < 4; ++c) s[qr][c] = vzero;
#pragma unroll
        for (int c = 0; c < 4; ++c) {
          bf16x8 kf[4];
#pragma unroll
          for (int kk = 0; kk < 4; ++kk)
            kf[kk] = *(const bf16x8*)&Ks[c*16 + lr][kk*32 + lkg*8];
#pragma unroll
          for (int qr = 0; qr < 2; ++qr)
#pragma unroll
            for (int kk = 0; kk < 4; ++kk)
              s[qr][c] = mfma16(qf[qr][kk], kf[kk], s[qr][c]);
        }
#pragma unroll
        for (int qr = 0; qr < 2; ++qr) {
          float scl4[4];
#pragma unroll
          for (int reg = 0; reg < 4; ++reg) {
            const int row = q0w + qr*16 + lkg*4 + reg;
            float v0 = (kbase      + lr <= row) ? s[qr][0][reg] : -INFINITY;
            float v1 = (kbase + 16 + lr <= row) ? s[qr][1][reg] : -INFINITY;
            float v2 = (kbase + 32 + lr <= row) ? s[qr][2][reg] : -INFINITY;
            float v3 = (kbase + 48 + lr <= row) ? s[qr][3][reg] : -INFINITY;
            float tm = fmaxf(fmaxf(v0, v1), fmaxf(v2, v3));
            tm = fmaxf(tm, __shfl_xor(tm, 1));
            tm = fmaxf(tm, __shfl_xor(tm, 2));
            tm = fmaxf(tm, __shfl_xor(tm, 4));
            tm = fmaxf(tm, __shfl_xor(tm, 8));
            const float mnew = fmaxf(mrow[qr][reg], tm);
            const float scl  = __expf(mrow[qr][reg] - mnew);
            mrow[qr][reg] = mnew;
            float p0 = __expf(v0 - mnew);
            float p1 = __expf(v1 - mnew);
            float p2 = __expf(v2 - mnew);
            float p3 = __expf(v3 - mnew);
            float rs = (p0 + p1) + (p2 + p3);
            rs += __shfl_xor(rs, 1);
            rs += __shfl_xor(rs, 2);
            rs += __shfl_xor(rs, 4);
            rs += __shfl_xor(rs, 8);
            lrow[qr][reg] = lrow[qr][reg] * scl + rs;
            scl4[reg] = scl;
            const int prow = qr*16 + lkg*4 + reg;
            Ps[wid][prow][lr]      = __float2bfloat16(p0);
            Ps[wid][prow][16 + lr] = __float2bfloat16(p1);
            Ps[wid][prow][32 + lr] = __float2bfloat16(p2);
            Ps[wid][prow][48 + lr] = __float2bfloat16(p3);
          }
#pragma unroll
          for (int db = 0; db < 8; ++db) {
            oacc[qr][db][0] *= scl4[0]; oacc[qr][db][1] *= scl4[1];
            oacc[qr][db][2] *= scl4[2]; oacc[qr][db][3] *= scl4[3];
          }
        }
        asm volatile("s_waitcnt lgkmcnt(0)" ::: "memory");
        __builtin_amdgcn_sched_barrier(0);
        bf16x8 pf[2][2];
#pragma unroll
        for (int qr = 0; qr < 2; ++qr)
#pragma unroll
          for (int k2 = 0; k2 < 2; ++k2)
            pf[qr][k2] = *(const bf16x8*)&Ps[wid][qr*16 + lr][k2*32 + lkg*8];
#pragma unroll
        for (int db = 0; db < 8; ++db) {
          bf16x8 vf0 = *(const bf16x8*)&Vs[db*16 + lr][lkg*8];
          bf16x8 vf1 = *(const bf16x8*)&Vs[db*16 + lr][32 + lkg*8];
#pragma unroll
          for (int qr = 0; qr < 2; ++qr) {
            oacc[qr][db] = mfma16(pf[qr][0], vf0, oacc[qr][db]);
            oacc[qr][db] = mfma16(pf[qr][1], vf1, oacc[qr][db]);
          }
        }
      }
    }

#pragma unroll
    for (int qr = 0; qr < 2; ++qr)
#pragma unroll
      for (int reg = 0; reg < 4; ++reg) {
        const float inv = 1.0f / lrow[qr][reg];
        const int row = q0w + qr*16 + lkg*4 + reg;
        bf16* dst = attnA + ((size_t)(b*LL + row)) * MODEL + h * HDIM;
#pragma unroll
        for (int db = 0; db < 8; ++db)
          dst[db*16 + lr] = __float2bfloat16(oacc[qr][db][reg] * inv);
      }
  }
}

// ---------------- launch ----------------
extern "C" void kernel_launch(void* const* d_in, const int* in_sizes, int n_in,
                              void* d_out, int out_size, void* d_ws, size_t ws_size,
                              hipStream_t stream)
{
  const float* x    = (const float*)d_in[0];
  const float* cosT = (const float*)d_in[1];
  const float* sinT = (const float*)d_in[2];
  const float* Wqkv = (const float*)d_in[3];
  const float* Wc   = (const float*)d_in[4];
  const float* bc   = (const float*)d_in[5];
  float* out = (float*)d_out;

  // workspace layout (bytes):
  //   x16    @ 0         : 16,777,216   (reused as attnA later)
  //   WqkvT  @ 16777216  : 25,165,824
  //   WcT    @ 41943040  :  8,388,608
  //   Qb     @ 50331648  : 16,777,216
  //   Kb     @ 67108864  : 16,777,216
  //   VTb    @ 83886080  : 16,777,216   -> total 100,663,296 B
  if (ws_size < 100663296u) return;
  char* w = (char*)d_ws;
  bf16* x16   = (bf16*)(w);
  bf16* WqkvT = (bf16*)(w + (size_t)16777216);
  bf16* WcT   = (bf16*)(w + (size_t)41943040);
  bf16* Qb    = (bf16*)(w + (size_t)50331648);
  bf16* Kb    = (bf16*)(w + (size_t)67108864);
  bf16* VTb   = (bf16*)(w + (size_t)83886080);
  bf16* attnA = x16;   // overlay: x16 dead after GEMM1

  // allow 48KB dynamic LDS (idempotent; not a stream op -> capture-safe)
  hipFuncSetAttribute(reinterpret_cast<const void*>(&k_gemmP<1>),
                      hipFuncAttributeMaxDynamicSharedMemorySize, 49152);
  hipFuncSetAttribute(reinterpret_cast<const void*>(&k_gemmP<2>),
                      hipFuncAttributeMaxDynamicSharedMemorySize, 49152);

  k_cvt<<<(MTOT*MODEL/4 + 255)/256, 256, 0, stream>>>(x, x16, MTOT*MODEL/4);
  k_transpose<<<dim3(N1/32,    MODEL/32), 256, 0, stream>>>(Wqkv, WqkvT, MODEL, N1);
  k_transpose<<<dim3(MODEL/32, MODEL/32), 256, 0, stream>>>(Wc,   WcT,   MODEL, MODEL);

  // grid 48*32 = 1536 blocks (3 blocks/CU -> 2 exact rounds of 768)
  k_gemmP<1><<<(N1/128)*(MTOT/128), 512, 49152, stream>>>(
      x16, WqkvT, MTOT, N1, MODEL,
      nullptr, nullptr, Qb, Kb, VTb, cosT, sinT);

  // grid 8*32 = 256 blocks, uniform 17 tile-units each
  k_attn<<<dim3(8, BB*NHEAD), 256, 0, stream>>>(Qb, Kb, VTb, attnA);

  // grid 16*32 = 512 blocks
  k_gemmP<2><<<(MODEL/128)*(MTOT/128), 512, 49152, stream>>>(
      attnA, WcT, MTOT, MODEL, MODEL,
      out, bc, nullptr, nullptr, nullptr, nullptr, nullptr);
}

// Round 13
// 336.671 us; speedup vs baseline: 1.1543x; 1.0484x over previous
//
#include <hip/hip_runtime.h>
#include <hip/hip_bf16.h>

#define MODEL 2048
#define NHEAD 16
#define HDIM  128
#define BB    2
#define LL    2048
#define N1    (3*MODEL)      // 6144
#define MTOT  (BB*LL)        // 4096

typedef __hip_bfloat16 bf16;
typedef __attribute__((ext_vector_type(8))) short bf16x8;
typedef __attribute__((ext_vector_type(4))) float f32x4;

static __device__ __forceinline__ f32x4 mfma16(bf16x8 a, bf16x8 b, f32x4 c) {
  return __builtin_amdgcn_mfma_f32_16x16x32_bf16(a, b, c, 0, 0, 0);
}

// async global->LDS DMA, 16B per lane; LDS base wave-uniform, dest linear
static __device__ __forceinline__ void gl_lds16(const void* g, void* l) {
  __builtin_amdgcn_global_load_lds(
      (const __attribute__((address_space(1))) unsigned int*)g,
      (__attribute__((address_space(3))) unsigned int*)l, 16, 0, 0);
}

// ---------------- prep: f32 -> bf16 (vectorized x4) ----------------
__global__ void k_cvt(const float* __restrict__ in, bf16* __restrict__ out, int n4) {
  int i = blockIdx.x * blockDim.x + threadIdx.x;
  if (i < n4) {
    float4 v = ((const float4*)in)[i];
    bf16* o = out + (size_t)i * 4;
    o[0] = __float2bfloat16(v.x);
    o[1] = __float2bfloat16(v.y);
    o[2] = __float2bfloat16(v.z);
    o[3] = __float2bfloat16(v.w);
  }
}

// ---------------- prep: transpose f32 [R][C] -> bf16 [C][R] ----------------
__global__ __launch_bounds__(256)
void k_transpose(const float* __restrict__ in, bf16* __restrict__ out, int R, int C) {
  __shared__ float t[32][33];
  const int c0 = blockIdx.x * 32, r0 = blockIdx.y * 32;
  const int tx = threadIdx.x & 31;
  const int ty = threadIdx.x >> 5;   // 0..7
#pragma unroll
  for (int i = 0; i < 4; ++i)
    t[ty + 8*i][tx] = in[(size_t)(r0 + ty + 8*i) * C + c0 + tx];
  __syncthreads();
#pragma unroll
  for (int i = 0; i < 4; ++i)
    out[(size_t)(c0 + ty + 8*i) * R + r0 + tx] = __float2bfloat16(t[tx][ty + 8*i]);
}

// ====== 128xBN GEMM, BK=32, 3-buffer pipeline (r13) ======
// r12-proven skeleton (8 waves, lockstep tile, distributed staging +
// collective barrier per tile [r8 lesson], mod-3 buffer rotation with
// depth-2 staging [r12 safety derivation], slot swizzle [r6, 0-conflict],
// square XCD chunking [r12: per-XCD A = 4MB, L2-fit]).
// r13: BN templated. BN=256 for GEMM1: wave = 64x64 -> 16 MFMA per 8
// ds_read_b128 (ratio 2.0 vs 1.33) and per-tile sync amortized over 2x
// work; LDS 72KB (3 x (8K A + 16K B)) -> still 2 blocks/CU.
// BN=128 for GEMM2: r12-exact (48KB, 3 blocks/CU, full-machine 512 grid).
// EPI==1: RoPE + scatter Q/K row-major + V^T ; EPI==2: bias + f32 out.

#define BARRIER __builtin_amdgcn_s_barrier()
#define SCHED0  __builtin_amdgcn_sched_barrier(0)
#define PRIO1 __builtin_amdgcn_s_setprio(1)
#define PRIO0 __builtin_amdgcn_s_setprio(0)

template<int EPI, int BN>
__global__ __launch_bounds__(512, 4)
void k_gemmP(const bf16* __restrict__ A, const bf16* __restrict__ BT,
             int M, int N, int K,
             float* __restrict__ Cout, const float* __restrict__ bias,
             bf16* __restrict__ Qb, bf16* __restrict__ Kb, bf16* __restrict__ VTb,
             const float* __restrict__ cosT, const float* __restrict__ sinT)
{
  constexpr int ABUF = 8192;           // one A tile (128 rows x 64B)
  constexpr int BBUF = BN * 64;        // one B tile (BN rows x 64B)
  constexpr int AREG = 3 * ABUF;       // 24576
  constexpr int NF   = BN / 64;        // B frags per wave (2 or 4)
  constexpr int BGL  = BN / 128;       // gl_lds per B stage (1 or 2)
  extern __shared__ char smem[];       // 49152 (BN=128) / 73728 (BN=256)

  const int tid = threadIdx.x;
  const int wid = tid >> 6, lane = tid & 63;
  const int wm = wid >> 2, wn = wid & 3;       // wave grid 2(M) x 4(N)
  const int lr = lane & 15, lkg = lane >> 4;

  // XCD chunk map (bid%8 = XCD): XCD=(mquarter, nhalf) owns an
  // 8 m-tile x (nbx/2) n-tile chunk, m-inner traversal (A panel L2-fits).
  const int nbx = N / BN;
  const int xcd = blockIdx.x & 7;
  const int i   = blockIdx.x >> 3;
  const int m0 = (((xcd >> 1) << 3) + (i & 7)) << 7;
  const int n0 = ((xcd & 1) * (nbx >> 1) + (i >> 3)) * BN;

  // staging: source slot carries inverse swizzle; LDS dest linear
  const int scol = ((lane & 3) ^ ((lane >> 3) & 3)) * 8;   // bf16 elems
  const bf16* Asrc = A  + (size_t)(m0 + wid*16       + (lane >> 2)) * K + scol;
  const bf16* Bsrc = BT + (size_t)(n0 + wid*(BN/8)   + (lane >> 2)) * K + scol;

  auto stageA = [&](int t) {
    gl_lds16(Asrc + t*32, smem + (t % 3)*ABUF + wid*1024);
  };
  auto stageB = [&](int t) {
    const bf16* g = Bsrc + t*32;
    char* d = smem + AREG + (t % 3)*BBUF + wid*(BN*8);
    gl_lds16(g, d);
    if constexpr (BGL == 2) gl_lds16(g + (size_t)16*K, d + 1024);
  };

  // ds_read fragment bases (row = 64B, slot XOR-swizzled by row bits 1-2)
  const int slotX = (lkg ^ ((lr >> 1) & 3)) * 16;
  const int aBase = wm*4096 + lr*64 + slotX;        // rows wm*64 + mf*16 + lr
  const int bBase = wn*(BN*16) + lr*64 + slotX;     // rows wn*(BN/4) + nf*16 + lr

  const f32x4 vzero = {0.f, 0.f, 0.f, 0.f};
  f32x4 acc[4][NF];
#pragma unroll
  for (int ii = 0; ii < 4; ++ii)
#pragma unroll
    for (int j = 0; j < NF; ++j) acc[ii][j] = vzero;

  const int nt = K >> 5;              // K-tiles of 32 (>= 3)

  // prologue: stage tiles 0,1 -> wait until tile 0's loads complete
  stageA(0); stageB(0); stageA(1); stageB(1);
  if constexpr (BGL == 1) { asm volatile("s_waitcnt vmcnt(2)" ::: "memory"); }
  else                    { asm volatile("s_waitcnt vmcnt(3)" ::: "memory"); }
  SCHED0; BARRIER;

  for (int t = 0; t < nt; ++t) {
    const int bufA = (t % 3) * ABUF;
    const int bufB = AREG + (t % 3) * BBUF;
    const int ts   = (t + 2 < nt) ? t + 2 : nt - 1;   // clamp: same-data dup
    bf16x8 aFr[4], bFr[NF];

#pragma unroll
    for (int mf = 0; mf < 4; ++mf)
      aFr[mf] = *(const bf16x8*)(smem + bufA + aBase + mf*1024);
#pragma unroll
    for (int nf = 0; nf < NF; ++nf)
      bFr[nf] = *(const bf16x8*)(smem + bufB + bBase + nf*1024);
    stageA(ts); stageB(ts);

    asm volatile("s_waitcnt lgkmcnt(0)" ::: "memory");
    SCHED0;
    PRIO1;
#pragma unroll
    for (int mf = 0; mf < 4; ++mf)
#pragma unroll
      for (int nf = 0; nf < NF; ++nf)
        acc[mf][nf] = mfma16(aFr[mf], bFr[nf], acc[mf][nf]);
    PRIO0;
    // complete tile t+1's loads (only stage(t+2) stays in flight)
    if constexpr (BGL == 1) { asm volatile("s_waitcnt vmcnt(2)" ::: "memory"); }
    else                    { asm volatile("s_waitcnt vmcnt(3)" ::: "memory"); }
    SCHED0;
    BARRIER;                          // collective: tile t+1 visible to all
  }

  if constexpr (EPI == 1) {
    const float inv_sqrt_d = 0.08838834764831845f;  // 1/sqrt(128)
#pragma unroll
    for (int nf = 0; nf < NF; ++nf) {
      const int gcb = n0 + wn*(BN/4) + nf*16;       // wave-uniform, mult of 16
      const int section = gcb >> 11;                // 0=q 1=k 2=v
      const int cc = (gcb & 2047) + lr;
      const int h = cc >> 7, d = cc & 127;
#pragma unroll
      for (int mf = 0; mf < 4; ++mf) {
#pragma unroll
        for (int reg = 0; reg < 4; ++reg) {
          const int grow = m0 + wm*64 + mf*16 + lkg*4 + reg;
          const int bidx = grow >> 11, lseq = grow & 2047;
          float val = acc[mf][nf][reg];
          if (section < 2) {
            float p = __shfl_xor(val, 1);           // RoPE pair partner
            const int fi = d >> 1;
            float cv = cosT[(size_t)lseq * 64 + fi];
            float sv = sinT[(size_t)lseq * 64 + fi];
            float r = (d & 1) ? fmaf(p, sv, val * cv)
                              : fmaf(val, cv, -p * sv);
            if (section == 0) {
              r *= inv_sqrt_d;
              Qb[((size_t)(bidx*NHEAD + h) * LL + lseq) * HDIM + d] = __float2bfloat16(r);
            } else {
              Kb[((size_t)(bidx*NHEAD + h) * LL + lseq) * HDIM + d] = __float2bfloat16(r);
            }
          } else {
            VTb[((size_t)(bidx*NHEAD + h) * HDIM + d) * LL + lseq] = __float2bfloat16(val);
          }
        }
      }
    }
  } else {
#pragma unroll
    for (int nf = 0; nf < NF; ++nf) {
      const int gcol = n0 + wn*(BN/4) + nf*16 + lr;
      const float bv = bias[gcol];
#pragma unroll
      for (int mf = 0; mf < 4; ++mf) {
#pragma unroll
        for (int reg = 0; reg < 4; ++reg) {
          const int grow = m0 + wm*64 + mf*16 + lkg*4 + reg;
          Cout[(size_t)grow * N + gcol] = acc[mf][nf][reg] + bv;
        }
      }
    }
  }
}

// ---------------- flash attention: balanced q-tile pairing (r9 exact) --------
// Block bx handles q-tiles (15-bx) then (bx): per-block KV work uniform
// (17 tile-units) -> robust to ANY block->CU/XCD placement.
__global__ __launch_bounds__(256, 2)
void k_attn(const bf16* __restrict__ Qb, const bf16* __restrict__ Kb,
            const bf16* __restrict__ VTb, bf16* __restrict__ attnA)
{
  __shared__ bf16 Ks[64][136];
  __shared__ bf16 Vs[128][72];
  __shared__ bf16 Ps[4][32][72];

  const int bh  = blockIdx.y;
  const int bx  = blockIdx.x;                 // 0..7
  const int tid = threadIdx.x;
  const int wid = tid >> 6, lane = tid & 63;
  const int lr  = lane & 15, lkg = lane >> 4;

  const bf16* Qh = Qb  + (size_t)bh * LL * HDIM;
  const bf16* Kh = Kb  + (size_t)bh * LL * HDIM;
  const bf16* Vh = VTb + (size_t)bh * HDIM * LL;
  const int b = bh >> 4, h = bh & 15;
  const f32x4 vzero = {0.f, 0.f, 0.f, 0.f};

  for (int pp = 0; pp < 2; ++pp) {
    const int qt  = pp ? bx : (15 - bx);      // heavy tile first
    const int Q0  = qt * 128;
    const int q0w = Q0 + wid * 32;

    bf16x8 qf[2][4];
#pragma unroll
    for (int qr = 0; qr < 2; ++qr)
#pragma unroll
      for (int kk = 0; kk < 4; ++kk)
        qf[qr][kk] = *(const bf16x8*)(Qh + (size_t)(q0w + qr*16 + lr) * HDIM + kk*32 + lkg*8);

    f32x4 oacc[2][8];
#pragma unroll
    for (int qr = 0; qr < 2; ++qr)
#pragma unroll
      for (int db = 0; db < 8; ++db) oacc[qr][db] = vzero;
    float mrow[2][4], lrow[2][4];
#pragma unroll
    for (int qr = 0; qr < 2; ++qr)
#pragma unroll
      for (int r = 0; r < 4; ++r) { mrow[qr][r] = -INFINITY; lrow[qr][r] = 0.f; }

    const int NT = Q0 / 64 + 2;
    bf16x8 kpre[4], vpre[4];
#pragma unroll
    for (int j = 0; j < 4; ++j) {
      const int c = j*256 + tid;
      kpre[j] = *(const bf16x8*)(Kh + (size_t)(c >> 4) * HDIM + (c & 15) * 8);
      vpre[j] = *(const bf16x8*)(Vh + (size_t)(c >> 3) * LL + (c & 7) * 8);
    }

    for (int kt = 0; kt < NT; ++kt) {
      const int kbase = kt * 64;
      __syncthreads();
#pragma unroll
      for (int j = 0; j < 4; ++j) {
        const int c = j*256 + tid;
        *(bf16x8*)&Ks[c >> 4][(c & 15) * 8] = kpre[j];
        *(bf16x8*)&Vs[c >> 3][(c & 7) * 8]  = vpre[j];
      }
      __syncthreads();
      if (kt + 1 < NT) {
#pragma unroll
        for (int j = 0; j < 4; ++j) {
          const int c = j*256 + tid;
          kpre[j] = *(const bf16x8*)(Kh + (size_t)((kt+1)*64 + (c >> 4)) * HDIM + (c & 15) * 8);
          vpre[j] = *(const bf16x8*)(Vh + (size_t)(c >> 3) * LL + (kt+1)*64 + (c & 7) * 8);
        }
      }
      if (kbase <= q0w + 31) {
        f32x4 s[2][4];
#pragma unroll
        for (int qr = 0; qr < 2; ++qr)
#pragma unroll
          for (int c = 0; c < 4; ++c) s[qr][c] = vzero;
#pragma unroll
        for (int c = 0; c < 4; ++c) {
          bf16x8 kf[4];
#pragma unroll
          for (int kk = 0; kk < 4; ++kk)
            kf[kk] = *(const bf16x8*)&Ks[c*16 + lr][kk*32 + lkg*8];
#pragma unroll
          for (int qr = 0; qr < 2; ++qr)
#pragma unroll
            for (int kk = 0; kk < 4; ++kk)
              s[qr][c] = mfma16(qf[qr][kk], kf[kk], s[qr][c]);
        }
#pragma unroll
        for (int qr = 0; qr < 2; ++qr) {
          float scl4[4];
#pragma unroll
          for (int reg = 0; reg < 4; ++reg) {
            const int row = q0w + qr*16 + lkg*4 + reg;
            float v0 = (kbase      + lr <= row) ? s[qr][0][reg] : -INFINITY;
            float v1 = (kbase + 16 + lr <= row) ? s[qr][1][reg] : -INFINITY;
            float v2 = (kbase + 32 + lr <= row) ? s[qr][2][reg] : -INFINITY;
            float v3 = (kbase + 48 + lr <= row) ? s[qr][3][reg] : -INFINITY;
            float tm = fmaxf(fmaxf(v0, v1), fmaxf(v2, v3));
            tm = fmaxf(tm, __shfl_xor(tm, 1));
            tm = fmaxf(tm, __shfl_xor(tm, 2));
            tm = fmaxf(tm, __shfl_xor(tm, 4));
            tm = fmaxf(tm, __shfl_xor(tm, 8));
            const float mnew = fmaxf(mrow[qr][reg], tm);
            const float scl  = __expf(mrow[qr][reg] - mnew);
            mrow[qr][reg] = mnew;
            float p0 = __expf(v0 - mnew);
            float p1 = __expf(v1 - mnew);
            float p2 = __expf(v2 - mnew);
            float p3 = __expf(v3 - mnew);
            float rs = (p0 + p1) + (p2 + p3);
            rs += __shfl_xor(rs, 1);
            rs += __shfl_xor(rs, 2);
            rs += __shfl_xor(rs, 4);
            rs += __shfl_xor(rs, 8);
            lrow[qr][reg] = lrow[qr][reg] * scl + rs;
            scl4[reg] = scl;
            const int prow = qr*16 + lkg*4 + reg;
            Ps[wid][prow][lr]      = __float2bfloat16(p0);
            Ps[wid][prow][16 + lr] = __float2bfloat16(p1);
            Ps[wid][prow][32 + lr] = __float2bfloat16(p2);
            Ps[wid][prow][48 + lr] = __float2bfloat16(p3);
          }
#pragma unroll
          for (int db = 0; db < 8; ++db) {
            oacc[qr][db][0] *= scl4[0]; oacc[qr][db][1] *= scl4[1];
            oacc[qr][db][2] *= scl4[2]; oacc[qr][db][3] *= scl4[3];
          }
        }
        asm volatile("s_waitcnt lgkmcnt(0)" ::: "memory");
        __builtin_amdgcn_sched_barrier(0);
        bf16x8 pf[2][2];
#pragma unroll
        for (int qr = 0; qr < 2; ++qr)
#pragma unroll
          for (int k2 = 0; k2 < 2; ++k2)
            pf[qr][k2] = *(const bf16x8*)&Ps[wid][qr*16 + lr][k2*32 + lkg*8];
#pragma unroll
        for (int db = 0; db < 8; ++db) {
          bf16x8 vf0 = *(const bf16x8*)&Vs[db*16 + lr][lkg*8];
          bf16x8 vf1 = *(const bf16x8*)&Vs[db*16 + lr][32 + lkg*8];
#pragma unroll
          for (int qr = 0; qr < 2; ++qr) {
            oacc[qr][db] = mfma16(pf[qr][0], vf0, oacc[qr][db]);
            oacc[qr][db] = mfma16(pf[qr][1], vf1, oacc[qr][db]);
          }
        }
      }
    }

#pragma unroll
    for (int qr = 0; qr < 2; ++qr)
#pragma unroll
      for (int reg = 0; reg < 4; ++reg) {
        const float inv = 1.0f / lrow[qr][reg];
        const int row = q0w + qr*16 + lkg*4 + reg;
        bf16* dst = attnA + ((size_t)(b*LL + row)) * MODEL + h * HDIM;
#pragma unroll
        for (int db = 0; db < 8; ++db)
          dst[db*16 + lr] = __float2bfloat16(oacc[qr][db][reg] * inv);
      }
  }
}

// ---------------- launch ----------------
extern "C" void kernel_launch(void* const* d_in, const int* in_sizes, int n_in,
                              void* d_out, int out_size, void* d_ws, size_t ws_size,
                              hipStream_t stream)
{
  const float* x    = (const float*)d_in[0];
  const float* cosT = (const float*)d_in[1];
  const float* sinT = (const float*)d_in[2];
  const float* Wqkv = (const float*)d_in[3];
  const float* Wc   = (const float*)d_in[4];
  const float* bc   = (const float*)d_in[5];
  float* out = (float*)d_out;

  // workspace layout (bytes):
  //   x16    @ 0         : 16,777,216   (reused as attnA later)
  //   WqkvT  @ 16777216  : 25,165,824
  //   WcT    @ 41943040  :  8,388,608
  //   Qb     @ 50331648  : 16,777,216
  //   Kb     @ 67108864  : 16,777,216
  //   VTb    @ 83886080  : 16,777,216   -> total 100,663,296 B
  if (ws_size < 100663296u) return;
  char* w = (char*)d_ws;
  bf16* x16   = (bf16*)(w);
  bf16* WqkvT = (bf16*)(w + (size_t)16777216);
  bf16* WcT   = (bf16*)(w + (size_t)41943040);
  bf16* Qb    = (bf16*)(w + (size_t)50331648);
  bf16* Kb    = (bf16*)(w + (size_t)67108864);
  bf16* VTb   = (bf16*)(w + (size_t)83886080);
  bf16* attnA = x16;   // overlay: x16 dead after GEMM1

  // allow dynamic LDS (idempotent; not a stream op -> capture-safe)
  hipFuncSetAttribute(reinterpret_cast<const void*>((&k_gemmP<1,256>)),
                      hipFuncAttributeMaxDynamicSharedMemorySize, 73728);
  hipFuncSetAttribute(reinterpret_cast<const void*>((&k_gemmP<2,128>)),
                      hipFuncAttributeMaxDynamicSharedMemorySize, 49152);

  k_cvt<<<(MTOT*MODEL/4 + 255)/256, 256, 0, stream>>>(x, x16, MTOT*MODEL/4);
  k_transpose<<<dim3(N1/32,    MODEL/32), 256, 0, stream>>>(Wqkv, WqkvT, MODEL, N1);
  k_transpose<<<dim3(MODEL/32, MODEL/32), 256, 0, stream>>>(Wc,   WcT,   MODEL, MODEL);

  // grid 32*24 = 768 blocks (2 blocks/CU, 1.5 rounds)
  k_gemmP<1,256><<<(MTOT/128)*(N1/256), 512, 73728, stream>>>(
      x16, WqkvT, MTOT, N1, MODEL,
      nullptr, nullptr, Qb, Kb, VTb, cosT, sinT);

  // grid 8*32 = 256 blocks, uniform 17 tile-units each
  k_attn<<<dim3(8, BB*NHEAD), 256, 0, stream>>>(Qb, Kb, VTb, attnA);

  // grid 32*16 = 512 blocks (3 blocks/CU, r12-exact)
  k_gemmP<2,128><<<(MTOT/128)*(MODEL/128), 512, 49152, stream>>>(
      attnA, WcT, MTOT, MODEL, MODEL,
      out, bc, nullptr, nullptr, nullptr, nullptr, nullptr);
}

// Round 14
// 297.090 us; speedup vs baseline: 1.3081x; 1.1332x over previous
//
#include <hip/hip_runtime.h>
#include <hip/hip_bf16.h>

#define MODEL 2048
#define NHEAD 16
#define HDIM  128
#define BB    2
#define LL    2048
#define N1    (3*MODEL)      // 6144
#define MTOT  (BB*LL)        // 4096

typedef __hip_bfloat16 bf16;
typedef __attribute__((ext_vector_type(8))) short bf16x8;
typedef __attribute__((ext_vector_type(4))) float f32x4;

static __device__ __forceinline__ f32x4 mfma16(bf16x8 a, bf16x8 b, f32x4 c) {
  return __builtin_amdgcn_mfma_f32_16x16x32_bf16(a, b, c, 0, 0, 0);
}

// async global->LDS DMA, 16B per lane; LDS base wave-uniform, dest linear
static __device__ __forceinline__ void gl_lds16(const void* g, void* l) {
  __builtin_amdgcn_global_load_lds(
      (const __attribute__((address_space(1))) unsigned int*)g,
      (__attribute__((address_space(3))) unsigned int*)l, 16, 0, 0);
}

static __device__ __forceinline__ unsigned bfu(float x) {
  bf16 b = __float2bfloat16(x);
  return (unsigned)*reinterpret_cast<unsigned short*>(&b);
}

// ---------------- prep: f32 -> bf16 (vectorized x4) ----------------
__global__ void k_cvt(const float* __restrict__ in, bf16* __restrict__ out, int n4) {
  int i = blockIdx.x * blockDim.x + threadIdx.x;
  if (i < n4) {
    float4 v = ((const float4*)in)[i];
    bf16* o = out + (size_t)i * 4;
    o[0] = __float2bfloat16(v.x);
    o[1] = __float2bfloat16(v.y);
    o[2] = __float2bfloat16(v.z);
    o[3] = __float2bfloat16(v.w);
  }
}

// ---------------- prep: transpose f32 [R][C] -> bf16 [C][R] ----------------
__global__ __launch_bounds__(256)
void k_transpose(const float* __restrict__ in, bf16* __restrict__ out, int R, int C) {
  __shared__ float t[32][33];
  const int c0 = blockIdx.x * 32, r0 = blockIdx.y * 32;
  const int tx = threadIdx.x & 31;
  const int ty = threadIdx.x >> 5;   // 0..7
#pragma unroll
  for (int i = 0; i < 4; ++i)
    t[ty + 8*i][tx] = in[(size_t)(r0 + ty + 8*i) * C + c0 + tx];
  __syncthreads();
#pragma unroll
  for (int i = 0; i < 4; ++i)
    out[(size_t)(c0 + ty + 8*i) * R + r0 + tx] = __float2bfloat16(t[tx][ty + 8*i]);
}

// ====== 128x128 GEMM, BK=32, 3-buffer pipeline, 3 blocks/CU (r12-exact) ======
// 8 waves 2Mx4N, lockstep tile, distributed staging + collective barrier per
// tile [r8 lesson], mod-3 rotation with depth-2 staging [r12 safety], slot
// swizzle [r6, 0-conflict], square XCD chunking [r12: per-XCD A L2-fits].
// EPI==1: RoPE + scatter Q/K row-major + V^T ; EPI==2: bias + f32 out.

#define BARRIER __builtin_amdgcn_s_barrier()
#define SCHED0  __builtin_amdgcn_sched_barrier(0)
#define PRIO1 __builtin_amdgcn_s_setprio(1)
#define PRIO0 __builtin_amdgcn_s_setprio(0)

template<int EPI>
__global__ __launch_bounds__(512, 4)
void k_gemmP(const bf16* __restrict__ A, const bf16* __restrict__ BT,
             int M, int N, int K,
             float* __restrict__ Cout, const float* __restrict__ bias,
             bf16* __restrict__ Qb, bf16* __restrict__ Kb, bf16* __restrict__ VTb,
             const float* __restrict__ cosT, const float* __restrict__ sinT)
{
  constexpr int ABUF = 8192;           // one A tile (128 rows x 64B)
  constexpr int BBUF = 8192;
  constexpr int AREG = 3 * ABUF;       // 24576
  extern __shared__ char smem[];       // 49152 B

  const int tid = threadIdx.x;
  const int wid = tid >> 6, lane = tid & 63;
  const int wm = wid >> 2, wn = wid & 3;       // wave grid 2(M) x 4(N)
  const int lr = lane & 15, lkg = lane >> 4;

  // XCD chunk map (bid%8 = XCD): XCD=(mquarter, nhalf) owns an
  // 8 m-tile x (nbx/2) n-tile chunk, m-inner traversal (A panel L2-fits).
  const int nbx = N >> 7;
  const int xcd = blockIdx.x & 7;
  const int i   = blockIdx.x >> 3;
  const int m0 = (((xcd >> 1) << 3) + (i & 7)) << 7;
  const int n0 = ((xcd & 1) * (nbx >> 1) + (i >> 3)) << 7;

  // staging: wave wid owns 16 rows; source slot carries inverse swizzle
  const int scol = ((lane & 3) ^ ((lane >> 3) & 3)) * 8;   // bf16 elems
  const bf16* Asrc = A  + (size_t)(m0 + wid*16 + (lane >> 2)) * K + scol;
  const bf16* Bsrc = BT + (size_t)(n0 + wid*16 + (lane >> 2)) * K + scol;

  auto stageA = [&](int t) {
    gl_lds16(Asrc + t*32, smem + (t % 3)*ABUF + wid*1024);
  };
  auto stageB = [&](int t) {
    gl_lds16(Bsrc + t*32, smem + AREG + (t % 3)*BBUF + wid*1024);
  };

  // ds_read fragment bases (row = 64B, slot XOR-swizzled by row bits 1-2)
  const int slotX = (lkg ^ ((lr >> 1) & 3)) * 16;
  const int aBase = wm*4096 + lr*64 + slotX;   // rows wm*64 + mf*16 + lr
  const int bBase = wn*2048 + lr*64 + slotX;   // rows wn*32 + nf*16 + lr

  const f32x4 vzero = {0.f, 0.f, 0.f, 0.f};
  f32x4 acc[4][2];
#pragma unroll
  for (int ii = 0; ii < 4; ++ii)
#pragma unroll
    for (int j = 0; j < 2; ++j) acc[ii][j] = vzero;

  const int nt = K >> 5;              // K-tiles of 32 (>= 3)

  // prologue: stage tiles 0,1 -> wait until tile 0's 2 loads complete
  stageA(0); stageB(0); stageA(1); stageB(1);
  asm volatile("s_waitcnt vmcnt(2)" ::: "memory");
  SCHED0; BARRIER;

  for (int t = 0; t < nt; ++t) {
    const int bufA = (t % 3) * ABUF;
    const int bufB = AREG + (t % 3) * BBUF;
    const int ts   = (t + 2 < nt) ? t + 2 : nt - 1;   // clamp: same-data dup
    bf16x8 aFr[4], bFr[2];

#pragma unroll
    for (int mf = 0; mf < 4; ++mf)
      aFr[mf] = *(const bf16x8*)(smem + bufA + aBase + mf*1024);
#pragma unroll
    for (int nf = 0; nf < 2; ++nf)
      bFr[nf] = *(const bf16x8*)(smem + bufB + bBase + nf*1024);
    stageA(ts); stageB(ts);

    asm volatile("s_waitcnt lgkmcnt(0)" ::: "memory");
    SCHED0;
    PRIO1;
#pragma unroll
    for (int mf = 0; mf < 4; ++mf)
#pragma unroll
      for (int nf = 0; nf < 2; ++nf)
        acc[mf][nf] = mfma16(aFr[mf], bFr[nf], acc[mf][nf]);
    PRIO0;
    // complete tile t+1's loads (only stage(t+2)'s 2 loads stay in flight)
    asm volatile("s_waitcnt vmcnt(2)" ::: "memory");
    SCHED0;
    BARRIER;                          // collective: tile t+1 visible to all
  }

  if constexpr (EPI == 1) {
    const float inv_sqrt_d = 0.08838834764831845f;  // 1/sqrt(128)
#pragma unroll
    for (int nf = 0; nf < 2; ++nf) {
      const int gcb = n0 + wn*32 + nf*16;           // wave-uniform, mult of 16
      const int section = gcb >> 11;                // 0=q 1=k 2=v
      const int cc = (gcb & 2047) + lr;
      const int h = cc >> 7, d = cc & 127;
#pragma unroll
      for (int mf = 0; mf < 4; ++mf) {
#pragma unroll
        for (int reg = 0; reg < 4; ++reg) {
          const int grow = m0 + wm*64 + mf*16 + lkg*4 + reg;
          const int bidx = grow >> 11, lseq = grow & 2047;
          float val = acc[mf][nf][reg];
          if (section < 2) {
            float p = __shfl_xor(val, 1);           // RoPE pair partner
            const int fi = d >> 1;
            float cv = cosT[(size_t)lseq * 64 + fi];
            float sv = sinT[(size_t)lseq * 64 + fi];
            float r = (d & 1) ? fmaf(p, sv, val * cv)
                              : fmaf(val, cv, -p * sv);
            if (section == 0) {
              r *= inv_sqrt_d;
              Qb[((size_t)(bidx*NHEAD + h) * LL + lseq) * HDIM + d] = __float2bfloat16(r);
            } else {
              Kb[((size_t)(bidx*NHEAD + h) * LL + lseq) * HDIM + d] = __float2bfloat16(r);
            }
          } else {
            VTb[((size_t)(bidx*NHEAD + h) * HDIM + d) * LL + lseq] = __float2bfloat16(val);
          }
        }
      }
    }
  } else {
#pragma unroll
    for (int nf = 0; nf < 2; ++nf) {
      const int gcol = n0 + wn*32 + nf*16 + lr;
      const float bv = bias[gcol];
#pragma unroll
      for (int mf = 0; mf < 4; ++mf) {
#pragma unroll
        for (int reg = 0; reg < 4; ++reg) {
          const int grow = m0 + wm*64 + mf*16 + lkg*4 + reg;
          Cout[(size_t)grow * N + gcol] = acc[mf][nf][reg] + bv;
        }
      }
    }
  }
}

// ---------------- flash attention (r14): swapped QK^T, lane-local softmax ----
// s2 = mfma(K,Q): lane (lr,lkg) holds S[q=lr][kv=c*16+lkg*4+reg] -> the full
// kv-row of one q-row is 16 lane-LOCAL values + 2 shfl (xor16/32 over lkg).
// P packs 4 contiguous bf16 per c -> ds_write_b64 (was 16 scalar b16 writes).
// PV/oacc layout unchanged (A-frag rows stay lr-indexed). Scale/norm factors
// broadcast to (lkg*4+reg)-rows via 4 __shfl. Balanced q-tile pairing (r9).
__global__ __launch_bounds__(256, 2)
void k_attn(const bf16* __restrict__ Qb, const bf16* __restrict__ Kb,
            const bf16* __restrict__ VTb, bf16* __restrict__ attnA)
{
  __shared__ bf16 Ks[64][136];
  __shared__ bf16 Vs[128][72];
  __shared__ bf16 Ps[4][32][72];

  const int bh  = blockIdx.y;
  const int bx  = blockIdx.x;                 // 0..7
  const int tid = threadIdx.x;
  const int wid = tid >> 6, lane = tid & 63;
  const int lr  = lane & 15, lkg = lane >> 4;

  const bf16* Qh = Qb  + (size_t)bh * LL * HDIM;
  const bf16* Kh = Kb  + (size_t)bh * LL * HDIM;
  const bf16* Vh = VTb + (size_t)bh * HDIM * LL;
  const int b = bh >> 4, h = bh & 15;
  const f32x4 vzero = {0.f, 0.f, 0.f, 0.f};

  for (int pp = 0; pp < 2; ++pp) {
    const int qt  = pp ? bx : (15 - bx);      // heavy tile first
    const int Q0  = qt * 128;
    const int q0w = Q0 + wid * 32;

    bf16x8 qf[2][4];
#pragma unroll
    for (int qr = 0; qr < 2; ++qr)
#pragma unroll
      for (int kk = 0; kk < 4; ++kk)
        qf[qr][kk] = *(const bf16x8*)(Qh + (size_t)(q0w + qr*16 + lr) * HDIM + kk*32 + lkg*8);

    f32x4 oacc[2][8];
#pragma unroll
    for (int qr = 0; qr < 2; ++qr)
#pragma unroll
      for (int db = 0; db < 8; ++db) oacc[qr][db] = vzero;
    // per-lane online-softmax state for q-row (q0w + qr*16 + lr)
    float ml[2] = {-INFINITY, -INFINITY};
    float ll[2] = {0.f, 0.f};

    const int NT = Q0 / 64 + 2;
    bf16x8 kpre[4], vpre[4];
#pragma unroll
    for (int j = 0; j < 4; ++j) {
      const int c = j*256 + tid;
      kpre[j] = *(const bf16x8*)(Kh + (size_t)(c >> 4) * HDIM + (c & 15) * 8);
      vpre[j] = *(const bf16x8*)(Vh + (size_t)(c >> 3) * LL + (c & 7) * 8);
    }

    for (int kt = 0; kt < NT; ++kt) {
      const int kbase = kt * 64;
      __syncthreads();
#pragma unroll
      for (int j = 0; j < 4; ++j) {
        const int c = j*256 + tid;
        *(bf16x8*)&Ks[c >> 4][(c & 15) * 8] = kpre[j];
        *(bf16x8*)&Vs[c >> 3][(c & 7) * 8]  = vpre[j];
      }
      __syncthreads();
      if (kt + 1 < NT) {
#pragma unroll
        for (int j = 0; j < 4; ++j) {
          const int c = j*256 + tid;
          kpre[j] = *(const bf16x8*)(Kh + (size_t)((kt+1)*64 + (c >> 4)) * HDIM + (c & 15) * 8);
          vpre[j] = *(const bf16x8*)(Vh + (size_t)(c >> 3) * LL + (kt+1)*64 + (c & 7) * 8);
        }
      }
      if (kbase <= q0w + 31) {
        // ---- S = K Q^T (swapped): lane holds S[q=lr][kv=c*16+lkg*4+reg] ----
        f32x4 s2[2][4];
#pragma unroll
        for (int qr = 0; qr < 2; ++qr)
#pragma unroll
          for (int c = 0; c < 4; ++c) s2[qr][c] = vzero;
#pragma unroll
        for (int c = 0; c < 4; ++c) {
          bf16x8 kf[4];
#pragma unroll
          for (int kk = 0; kk < 4; ++kk)
            kf[kk] = *(const bf16x8*)&Ks[c*16 + lr][kk*32 + lkg*8];
#pragma unroll
          for (int qr = 0; qr < 2; ++qr)
#pragma unroll
            for (int kk = 0; kk < 4; ++kk)
              s2[qr][c] = mfma16(kf[kk], qf[qr][kk], s2[qr][c]);
        }
        // ---- lane-local online softmax per qr ----
#pragma unroll
        for (int qr = 0; qr < 2; ++qr) {
          const int qrow = q0w + qr*16 + lr;
          float pv[4][4];
#pragma unroll
          for (int c = 0; c < 4; ++c)
#pragma unroll
            for (int reg = 0; reg < 4; ++reg) {
              const int kv = kbase + c*16 + lkg*4 + reg;
              pv[c][reg] = (kv <= qrow) ? s2[qr][c][reg] : -INFINITY;
            }
          float tm = pv[0][0];
#pragma unroll
          for (int c = 0; c < 4; ++c)
#pragma unroll
            for (int reg = 0; reg < 4; ++reg)
              if (c || reg) tm = fmaxf(tm, pv[c][reg]);
          tm = fmaxf(tm, __shfl_xor(tm, 16));
          tm = fmaxf(tm, __shfl_xor(tm, 32));
          const float mnew = fmaxf(ml[qr], tm);
          const float scl  = __expf(ml[qr] - mnew);   // first tile: exp(-inf)=0
          ml[qr] = mnew;
          float rs = 0.f;
#pragma unroll
          for (int c = 0; c < 4; ++c)
#pragma unroll
            for (int reg = 0; reg < 4; ++reg) {
              pv[c][reg] = __expf(pv[c][reg] - mnew);
              rs += pv[c][reg];
            }
          rs += __shfl_xor(rs, 16);
          rs += __shfl_xor(rs, 32);
          ll[qr] = ll[qr] * scl + rs;
          // pack 4 contiguous bf16 per c -> one 8B write
#pragma unroll
          for (int c = 0; c < 4; ++c) {
            unsigned lo = bfu(pv[c][0]) | (bfu(pv[c][1]) << 16);
            unsigned hi = bfu(pv[c][2]) | (bfu(pv[c][3]) << 16);
            *(uint2*)&Ps[wid][qr*16 + lr][c*16 + lkg*4] = make_uint2(lo, hi);
          }
          // broadcast scale to the rows this lane accumulates (lkg*4+reg)
          float sr[4];
#pragma unroll
          for (int reg = 0; reg < 4; ++reg) sr[reg] = __shfl(scl, lkg*4 + reg);
#pragma unroll
          for (int db = 0; db < 8; ++db) {
            oacc[qr][db][0] *= sr[0]; oacc[qr][db][1] *= sr[1];
            oacc[qr][db][2] *= sr[2]; oacc[qr][db][3] *= sr[3];
          }
        }
        // wave-private P write -> read
        asm volatile("s_waitcnt lgkmcnt(0)" ::: "memory");
        __builtin_amdgcn_sched_barrier(0);
        bf16x8 pf[2][2];
#pragma unroll
        for (int qr = 0; qr < 2; ++qr)
#pragma unroll
          for (int k2 = 0; k2 < 2; ++k2)
            pf[qr][k2] = *(const bf16x8*)&Ps[wid][qr*16 + lr][k2*32 + lkg*8];
#pragma unroll
        for (int db = 0; db < 8; ++db) {
          bf16x8 vf0 = *(const bf16x8*)&Vs[db*16 + lr][lkg*8];
          bf16x8 vf1 = *(const bf16x8*)&Vs[db*16 + lr][32 + lkg*8];
#pragma unroll
          for (int qr = 0; qr < 2; ++qr) {
            oacc[qr][db] = mfma16(pf[qr][0], vf0, oacc[qr][db]);
            oacc[qr][db] = mfma16(pf[qr][1], vf1, oacc[qr][db]);
          }
        }
      }
    }

#pragma unroll
    for (int qr = 0; qr < 2; ++qr) {
      const float myinv = 1.0f / ll[qr];
      float li[4];
#pragma unroll
      for (int reg = 0; reg < 4; ++reg) li[reg] = __shfl(myinv, lkg*4 + reg);
#pragma unroll
      for (int reg = 0; reg < 4; ++reg) {
        const int row = q0w + qr*16 + lkg*4 + reg;
        bf16* dst = attnA + ((size_t)(b*LL + row)) * MODEL + h * HDIM;
#pragma unroll
        for (int db = 0; db < 8; ++db)
          dst[db*16 + lr] = __float2bfloat16(oacc[qr][db][reg] * li[reg]);
      }
    }
  }
}

// ---------------- launch ----------------
extern "C" void kernel_launch(void* const* d_in, const int* in_sizes, int n_in,
                              void* d_out, int out_size, void* d_ws, size_t ws_size,
                              hipStream_t stream)
{
  const float* x    = (const float*)d_in[0];
  const float* cosT = (const float*)d_in[1];
  const float* sinT = (const float*)d_in[2];
  const float* Wqkv = (const float*)d_in[3];
  const float* Wc   = (const float*)d_in[4];
  const float* bc   = (const float*)d_in[5];
  float* out = (float*)d_out;

  // workspace layout (bytes):
  //   x16    @ 0         : 16,777,216   (reused as attnA later)
  //   WqkvT  @ 16777216  : 25,165,824
  //   WcT    @ 41943040  :  8,388,608
  //   Qb     @ 50331648  : 16,777,216
  //   Kb     @ 67108864  : 16,777,216
  //   VTb    @ 83886080  : 16,777,216   -> total 100,663,296 B
  if (ws_size < 100663296u) return;
  char* w = (char*)d_ws;
  bf16* x16   = (bf16*)(w);
  bf16* WqkvT = (bf16*)(w + (size_t)16777216);
  bf16* WcT   = (bf16*)(w + (size_t)41943040);
  bf16* Qb    = (bf16*)(w + (size_t)50331648);
  bf16* Kb    = (bf16*)(w + (size_t)67108864);
  bf16* VTb   = (bf16*)(w + (size_t)83886080);
  bf16* attnA = x16;   // overlay: x16 dead after GEMM1

  // allow 48KB dynamic LDS (idempotent; not a stream op -> capture-safe)
  hipFuncSetAttribute(reinterpret_cast<const void*>(&k_gemmP<1>),
                      hipFuncAttributeMaxDynamicSharedMemorySize, 49152);
  hipFuncSetAttribute(reinterpret_cast<const void*>(&k_gemmP<2>),
                      hipFuncAttributeMaxDynamicSharedMemorySize, 49152);

  k_cvt<<<(MTOT*MODEL/4 + 255)/256, 256, 0, stream>>>(x, x16, MTOT*MODEL/4);
  k_transpose<<<dim3(N1/32,    MODEL/32), 256, 0, stream>>>(Wqkv, WqkvT, MODEL, N1);
  k_transpose<<<dim3(MODEL/32, MODEL/32), 256, 0, stream>>>(Wc,   WcT,   MODEL, MODEL);

  // grid 48*32 = 1536 blocks (3 blocks/CU -> 2 exact rounds of 768)
  k_gemmP<1><<<(N1/128)*(MTOT/128), 512, 49152, stream>>>(
      x16, WqkvT, MTOT, N1, MODEL,
      nullptr, nullptr, Qb, Kb, VTb, cosT, sinT);

  // grid 8*32 = 256 blocks, uniform 17 tile-units each
  k_attn<<<dim3(8, BB*NHEAD), 256, 0, stream>>>(Qb, Kb, VTb, attnA);

  // grid 16*32 = 512 blocks
  k_gemmP<2><<<(MODEL/128)*(MTOT/128), 512, 49152, stream>>>(
      attnA, WcT, MTOT, MODEL, MODEL,
      out, bc, nullptr, nullptr, nullptr, nullptr, nullptr);
}